// Round 1
// baseline (294.348 us; speedup 1.0000x reference)
//
#include <hip/hip_runtime.h>
#include <hip/hip_bf16.h>
#include <cmath>

using f32x4 = __attribute__((ext_vector_type(4))) float;
using s16x8 = __attribute__((ext_vector_type(8))) short;

__device__ __forceinline__ float bf2f(unsigned short u){
  union { unsigned int i; float f; } v; v.i = ((unsigned int)u) << 16; return v.f;
}
__device__ __forceinline__ unsigned short f2bf(float f){
  union { float f; unsigned int i; } v; v.f = f;
  return (unsigned short)((v.i + 0x7FFFu + ((v.i >> 16) & 1u)) >> 16);
}

#define GLDS16(g, l) __builtin_amdgcn_global_load_lds( \
    (const __attribute__((address_space(1))) unsigned int*)(g), \
    (__attribute__((address_space(3))) unsigned int*)(l), 16, 0, 0)

// ---------------- CVT: feats f32 -> bf16 ----------------
__global__ void k_cvt(const float* __restrict__ x, unsigned short* __restrict__ xb, int n8){
  int idx = blockIdx.x * 256 + threadIdx.x;
  int stride = gridDim.x * 256;
  for (int e = idx; e < n8; e += stride){
    long b = (long)e * 8;
    f32x4 a0 = *(const f32x4*)(x + b);
    f32x4 a1 = *(const f32x4*)(x + b + 4);
    s16x8 r;
    #pragma unroll
    for (int j = 0; j < 4; j++){ r[j] = (short)f2bf(a0[j]); r[4+j] = (short)f2bf(a1[j]); }
    *(s16x8*)(xb + b) = r;
  }
}

// ---------------- h = gelu(Bl @ Wd^T + bd), (256,96) ----------------
__global__ void k_h(const float* __restrict__ Bp, const int* __restrict__ layerp,
                    const float* __restrict__ Wd, const float* __restrict__ bd,
                    float* __restrict__ h){
  __shared__ float brow[256];
  int i = blockIdx.x;
  const float* Bl = Bp + (long)(*layerp) * 256 * 256;
  for (int k = threadIdx.x; k < 256; k += blockDim.x) brow[k] = Bl[i*256 + k];
  __syncthreads();
  int j = threadIdx.x;
  if (j < 96){
    float acc = 0.f;
    for (int k = 0; k < 256; k++) acc += brow[k] * Wd[j*256 + k];
    float xx = acc + bd[j];
    h[i*96 + j] = 0.5f * xx * (1.0f + erff(xx * 0.70710678118654752f));
  }
}

// ---------------- Bf = h @ Wu^T + bu, (256,768) ----------------
__global__ void k_bfm(const float* __restrict__ h, const float* __restrict__ Wu,
                      const float* __restrict__ bu, float* __restrict__ Bfm){
  __shared__ float hrow[96];
  int i = blockIdx.x;
  if (threadIdx.x < 96) hrow[threadIdx.x] = h[i*96 + threadIdx.x];
  __syncthreads();
  for (int j = threadIdx.x; j < 768; j += 256){
    float acc = 0.f;
    for (int k = 0; k < 96; k++) acc += hrow[k] * Wu[j*96 + k];
    Bfm[i*768 + j] = acc + bu[j];
  }
}

// ---------------- tokens = A @ Bf, (100,768); tokensb bf16 padded to 112 rows ----------------
__global__ void k_tokens(const float* __restrict__ Ap, const float* __restrict__ Bfm,
                         float* __restrict__ tokens, unsigned short* __restrict__ tokensb){
  int i = blockIdx.x; // 0..111
  if (i < 100){
    __shared__ float arow[256];
    for (int k = threadIdx.x; k < 256; k += 256) arow[k] = Ap[i*256 + k];
    __syncthreads();
    for (int j = threadIdx.x; j < 768; j += 256){
      float acc = 0.f;
      for (int k = 0; k < 256; k++) acc += arow[k] * Bfm[k*768 + j];
      tokens[i*768 + j] = acc;
      tokensb[i*768 + j] = f2bf(acc);
    }
  } else {
    for (int j = threadIdx.x; j < 768; j += 256) tokensb[i*768 + j] = 0;
  }
}

// ---------------- t2f = tokens @ Wt^T + bt, (100,768) ----------------
__global__ void k_t2f(const float* __restrict__ tokens, const float* __restrict__ Wt,
                      const float* __restrict__ bt, float* __restrict__ t2f){
  __shared__ __align__(16) float trow[768];
  int i = blockIdx.x;
  for (int k = threadIdx.x; k < 768; k += 256) trow[k] = tokens[i*768 + k];
  __syncthreads();
  for (int j = threadIdx.x; j < 768; j += 256){
    const f32x4* wr = (const f32x4*)(Wt + (long)j * 768);
    const f32x4* tr = (const f32x4*)trow;
    float acc = 0.f;
    #pragma unroll 4
    for (int k = 0; k < 192; k++){
      f32x4 a = wr[k], c = tr[k];
      acc += a[0]*c[0] + a[1]*c[1] + a[2]*c[2] + a[3]*c[3];
    }
    t2f[i*768 + j] = acc + bt[j];
  }
}

// ---------------- WB[n][0..767]=bf16(Wf[n]), WB[n][768+m]=bf16(G'[m][n]=t2f[m]·Wf[n]), pad->896 ----------------
__global__ void k_wb(const float* __restrict__ Wf, const float* __restrict__ t2f,
                     unsigned short* __restrict__ WB){
  __shared__ __align__(16) float wrow[768];
  int n = blockIdx.x;
  for (int k = threadIdx.x; k < 768; k += 256){
    float v = Wf[(long)n*768 + k];
    wrow[k] = v;
    WB[(long)n*896 + k] = f2bf(v);
  }
  __syncthreads();
  for (int m = threadIdx.x; m < 128; m += 256){
    unsigned short val = 0;
    if (m < 100){
      const f32x4* tr = (const f32x4*)(t2f + (long)m * 768);
      const f32x4* wr = (const f32x4*)wrow;
      float acc = 0.f;
      #pragma unroll 4
      for (int k = 0; k < 192; k++){
        f32x4 a = tr[k], c = wr[k];
        acc += a[0]*c[0] + a[1]*c[1] + a[2]*c[2] + a[3]*c[3];
      }
      val = f2bf(acc);
    }
    WB[(long)n*896 + 768 + m] = val;
  }
}

// ---------------- logits + softmax -> Pbuf bf16 [32768][128] ----------------
__global__ __launch_bounds__(256) void k_attn(const unsigned short* __restrict__ xb,
    const unsigned short* __restrict__ tokensb, unsigned short* __restrict__ Pbuf){
  int tid = threadIdx.x;
  int w = tid >> 6, l = tid & 63;
  int l15 = l & 15, lhi = l >> 4;
  long wrowg = (long)blockIdx.x * 128 + w * 32; // wave covers 32 rows

  f32x4 acc[2][7];
  #pragma unroll
  for (int m = 0; m < 2; m++)
    #pragma unroll
    for (int nf = 0; nf < 7; nf++) acc[m][nf] = (f32x4)0.0f;

  for (int t = 0; t < 24; t++){
    int k0 = t*32 + lhi*8;
    s16x8 a[2], b[7];
    #pragma unroll
    for (int m = 0; m < 2; m++)
      a[m] = *(const s16x8*)(xb + (wrowg + m*16 + l15)*768 + k0);
    #pragma unroll
    for (int nf = 0; nf < 7; nf++)
      b[nf] = *(const s16x8*)(tokensb + (nf*16 + l15)*768 + k0);
    #pragma unroll
    for (int m = 0; m < 2; m++)
      #pragma unroll
      for (int nf = 0; nf < 7; nf++)
        acc[m][nf] = __builtin_amdgcn_mfma_f32_16x16x32_bf16(a[m], b[nf], acc[m][nf], 0, 0, 0);
  }

  const float sc = 0.03608439182435161f; // 768^-0.5
  #pragma unroll
  for (int m = 0; m < 2; m++){
    #pragma unroll
    for (int r = 0; r < 4; r++){
      float mx = -1e30f;
      #pragma unroll
      for (int nf = 0; nf < 7; nf++){
        int col = nf*16 + l15;
        float v = acc[m][nf][r] * sc;
        if (col < 100 && v > mx) mx = v;
      }
      mx = fmaxf(mx, __shfl_xor(mx, 1));
      mx = fmaxf(mx, __shfl_xor(mx, 2));
      mx = fmaxf(mx, __shfl_xor(mx, 4));
      mx = fmaxf(mx, __shfl_xor(mx, 8));
      float p[7];
      float sm = 0.f;
      #pragma unroll
      for (int nf = 0; nf < 7; nf++){
        int col = nf*16 + l15;
        float v = (col < 100) ? __expf(acc[m][nf][r]*sc - mx) : 0.f;
        p[nf] = v; sm += v;
      }
      sm += __shfl_xor(sm, 1);
      sm += __shfl_xor(sm, 2);
      sm += __shfl_xor(sm, 4);
      sm += __shfl_xor(sm, 8);
      float inv = 1.f / sm;
      long row = wrowg + m*16 + lhi*4 + r;
      #pragma unroll
      for (int nf = 0; nf < 7; nf++)
        Pbuf[row*128 + nf*16 + l15] = f2bf(p[nf] * inv);
      Pbuf[row*128 + 112 + l15] = 0;
    }
  }
}

// ---------------- big GEMM: out = feats + scale*([xb|P] @ WB^T + bf) ----------------
__global__ __launch_bounds__(256) void k_gemm(const unsigned short* __restrict__ xb,
    const unsigned short* __restrict__ Pbuf, const unsigned short* __restrict__ WB,
    const float* __restrict__ bfv, const float* __restrict__ scalep,
    float* __restrict__ outf){
  __shared__ __align__(16) unsigned short As[128*64];
  __shared__ __align__(16) unsigned short Bs[128*64];
  int bid = blockIdx.x;                 // 1536 = 8 XCD * 192
  int sid = (bid & 7) * 192 + (bid >> 3);
  int mt = sid / 6, nt = sid - mt*6;
  long brow = (long)mt * 128;
  int bcol = nt * 128;
  int tid = threadIdx.x, w = tid >> 6, l = tid & 63;
  int l15 = l & 15, lhi = l >> 4;
  int srow = l >> 3, scol = (l & 7) * 8;
  int wrow = (w >> 1) * 64, wcol = (w & 1) * 64;

  f32x4 acc[4][4];
  #pragma unroll
  for (int m = 0; m < 4; m++)
    #pragma unroll
    for (int n = 0; n < 4; n++) acc[m][n] = (f32x4)0.0f;

  for (int t = 0; t < 14; t++){
    __syncthreads();
    #pragma unroll
    for (int i = 0; i < 4; i++){
      int c = i*4 + w;
      int row = c*8 + srow;
      const unsigned short* ga = (t < 12)
        ? xb   + (brow + row)*768 + t*64 + scol
        : Pbuf + (brow + row)*128 + (t - 12)*64 + scol;
      GLDS16(ga, As + c*512);
      const unsigned short* gb = WB + (long)(bcol + row)*896 + t*64 + scol;
      GLDS16(gb, Bs + c*512);
    }
    __syncthreads();
    #pragma unroll
    for (int kk = 0; kk < 2; kk++){
      s16x8 a[4], b[4];
      #pragma unroll
      for (int m = 0; m < 4; m++)
        a[m] = *(const s16x8*)(As + (wrow + m*16 + l15)*64 + kk*32 + lhi*8);
      #pragma unroll
      for (int n = 0; n < 4; n++)
        b[n] = *(const s16x8*)(Bs + (wcol + n*16 + l15)*64 + kk*32 + lhi*8);
      #pragma unroll
      for (int m = 0; m < 4; m++)
        #pragma unroll
        for (int n = 0; n < 4; n++)
          acc[m][n] = __builtin_amdgcn_mfma_f32_16x16x32_bf16(a[m], b[n], acc[m][n], 0, 0, 0);
    }
  }

  float scale = *scalep;
  #pragma unroll
  for (int m = 0; m < 4; m++){
    #pragma unroll
    for (int n = 0; n < 4; n++){
      int gcol = bcol + wcol + n*16 + l15;
      float bias = bfv[gcol];
      #pragma unroll
      for (int r = 0; r < 4; r++){
        long grow = brow + wrow + m*16 + lhi*4 + r;
        float feat = bf2f(xb[grow*768 + gcol]);
        outf[grow*768 + gcol] = feat + scale * (acc[m][n][r] + bias);
      }
    }
  }
}

extern "C" void kernel_launch(void* const* d_in, const int* in_sizes, int n_in,
                              void* d_out, int out_size, void* d_ws, size_t ws_size,
                              hipStream_t stream) {
  const float* x   = (const float*)d_in[0];
  const float* Wd  = (const float*)d_in[1];
  const float* bd  = (const float*)d_in[2];
  const float* Wu  = (const float*)d_in[3];
  const float* bu  = (const float*)d_in[4];
  const float* Wt  = (const float*)d_in[5];
  const float* bt  = (const float*)d_in[6];
  const float* Wf  = (const float*)d_in[7];
  const float* bfv = (const float*)d_in[8];
  const float* Ap  = (const float*)d_in[9];
  const float* Bp  = (const float*)d_in[10];
  const float* scalep = (const float*)d_in[11];
  const int* layerp   = (const int*)d_in[12];
  float* out = (float*)d_out;

  char* ws = (char*)d_ws;
  unsigned short* xb      = (unsigned short*)(ws);              // 32768*768*2 = 50,331,648
  unsigned short* Pbuf    = (unsigned short*)(ws + 50331648);   // 32768*128*2 =  8,388,608
  unsigned short* WB      = (unsigned short*)(ws + 58720256);   // 768*896*2   =  1,376,256
  unsigned short* tokensb = (unsigned short*)(ws + 60096512);   // 112*768*2   =    172,032
  float* hbuf   = (float*)(ws + 60268544);                      // 256*96*4
  float* Bfm    = (float*)(ws + 60366848);                      // 256*768*4
  float* tokens = (float*)(ws + 61153280);                      // 100*768*4
  float* t2f    = (float*)(ws + 61460480);                      // 100*768*4

  const float* xf = x + 32*768;   // feats (skip cls token row)
  float* outf = out + 32*768;

  // cls passthrough
  hipMemcpyAsync(d_out, d_in[0], 32*768*sizeof(float), hipMemcpyDeviceToDevice, stream);

  k_cvt   <<<4096, 256, 0, stream>>>(xf, xb, 25165824/8);
  k_h     <<<256, 128, 0, stream>>>(Bp, layerp, Wd, bd, hbuf);
  k_bfm   <<<256, 256, 0, stream>>>(hbuf, Wu, bu, Bfm);
  k_tokens<<<112, 256, 0, stream>>>(Ap, Bfm, tokens, tokensb);
  k_t2f   <<<100, 256, 0, stream>>>(tokens, Wt, bt, t2f);
  k_wb    <<<768, 256, 0, stream>>>(Wf, t2f, WB);
  k_attn  <<<256, 256, 0, stream>>>(xb, tokensb, Pbuf);
  k_gemm  <<<1536, 256, 0, stream>>>(xb, Pbuf, WB, bfv, scalep, outf);
}

// Round 2
// 200.657 us; speedup vs baseline: 1.4669x; 1.4669x over previous
//
#include <hip/hip_runtime.h>
#include <hip/hip_bf16.h>
#include <cmath>

using f32x4 = __attribute__((ext_vector_type(4))) float;
using s16x8 = __attribute__((ext_vector_type(8))) short;

__device__ __forceinline__ float bf2f(unsigned short u){
  union { unsigned int i; float f; } v; v.i = ((unsigned int)u) << 16; return v.f;
}
__device__ __forceinline__ unsigned short f2bf(float f){
  union { float f; unsigned int i; } v; v.f = f;
  return (unsigned short)((v.i + 0x7FFFu + ((v.i >> 16) & 1u)) >> 16);
}

#define GLDS16(g, l) __builtin_amdgcn_global_load_lds( \
    (const __attribute__((address_space(1))) unsigned int*)(g), \
    (__attribute__((address_space(3))) unsigned int*)(l), 16, 0, 0)

// ---------------- prep: convert all small operands to bf16 ----------------
// y=0: Wd(96x256)->Wdb   y=1: Wu(768x96)->Wub   y=2: Wt(768x768)->Wtb
// y=3: Wf(768x768)->WB[:, :768] (stride 896), zero WB[:, 768:896]
// y=4: A(100x256)->Ab(112x256, pad rows 0)     y=5: Bp[layer](256x256)->Blb
__global__ void k_prep(const float* __restrict__ Wd, const float* __restrict__ Wu,
                       const float* __restrict__ Wt, const float* __restrict__ Wf,
                       const float* __restrict__ Ap, const float* __restrict__ Bp,
                       const int* __restrict__ layerp,
                       unsigned short* __restrict__ Wdb, unsigned short* __restrict__ Wub,
                       unsigned short* __restrict__ Wtb, unsigned short* __restrict__ WB,
                       unsigned short* __restrict__ Ab, unsigned short* __restrict__ Blb){
  int idx = blockIdx.x * 256 + threadIdx.x;
  switch (blockIdx.y){
    case 0: if (idx < 24576)  Wdb[idx] = f2bf(Wd[idx]); break;
    case 1: if (idx < 73728)  Wub[idx] = f2bf(Wu[idx]); break;
    case 2: if (idx < 589824) Wtb[idx] = f2bf(Wt[idx]); break;
    case 3: if (idx < 688128){
      int n = idx / 896, c = idx - n * 896;
      WB[idx] = (c < 768) ? f2bf(Wf[n * 768 + c]) : (unsigned short)0;
    } break;
    case 4: if (idx < 28672){
      int r = idx >> 8;
      Ab[idx] = (r < 100) ? f2bf(Ap[idx]) : (unsigned short)0;
    } break;
    case 5: if (idx < 65536) Blb[idx] = f2bf(Bp[(long)(*layerp) * 65536 + idx]); break;
  }
}

// ---------------- generic 1-wave MFMA mini-GEMM: out = epi(A @ B^T + bias) ----------------
// EPI 0: exact gelu, bf16 row-major (ldo)     EPI 1: bias, bf16 TRANSPOSED store (ldo = M)
// EPI 2: optional bias, bf16 row-major        EPI 3: store transposed into WB cols 768+, guard row<100
template<int EPI>
__global__ __launch_bounds__(64) void k_mm(const unsigned short* __restrict__ A, int lda,
    const unsigned short* __restrict__ B, int ldb, int K,
    const float* __restrict__ bias, unsigned short* __restrict__ out, int ldo){
  int l = threadIdx.x, l15 = l & 15, lhi = l >> 4;
  int m0 = blockIdx.x * 16, n0 = blockIdx.y * 16;
  f32x4 acc = (f32x4)0.0f;
  #pragma unroll 4
  for (int k0 = 0; k0 < K; k0 += 32){
    s16x8 a = *(const s16x8*)(A + (long)(m0 + l15) * lda + k0 + lhi * 8);
    s16x8 b = *(const s16x8*)(B + (long)(n0 + l15) * ldb + k0 + lhi * 8);
    acc = __builtin_amdgcn_mfma_f32_16x16x32_bf16(a, b, acc, 0, 0, 0);
  }
  int col = n0 + l15;
  float bv = bias ? bias[col] : 0.0f;
  #pragma unroll
  for (int r = 0; r < 4; r++){
    int row = m0 + lhi * 4 + r;
    float v = acc[r] + bv;
    if (EPI == 0){
      v = 0.5f * v * (1.0f + erff(v * 0.70710678118654752f));
      out[(long)row * ldo + col] = f2bf(v);
    } else if (EPI == 1){
      out[(long)col * ldo + row] = f2bf(v);
    } else if (EPI == 2){
      out[(long)row * ldo + col] = f2bf(v);
    } else {
      out[(long)col * 896 + 768 + row] = (row < 100) ? f2bf(v) : (unsigned short)0;
    }
  }
}

// ---------------- fused cvt + logits + softmax: reads f32 feats, writes xb + Pbuf ----------------
__global__ __launch_bounds__(256) void k_attn(const float* __restrict__ xf,
    const unsigned short* __restrict__ tokensb, unsigned short* __restrict__ xb,
    unsigned short* __restrict__ Pbuf){
  int tid = threadIdx.x;
  int w = tid >> 6, l = tid & 63;
  int l15 = l & 15, lhi = l >> 4;
  long wrowg = (long)blockIdx.x * 64 + w * 16;   // wave covers 16 rows

  f32x4 acc[7];
  #pragma unroll
  for (int nf = 0; nf < 7; nf++) acc[nf] = (f32x4)0.0f;

  long row = wrowg + l15;
  for (int t = 0; t < 24; t++){
    int k0 = t * 32 + lhi * 8;
    f32x4 x0 = *(const f32x4*)(xf + row * 768 + k0);
    f32x4 x1 = *(const f32x4*)(xf + row * 768 + k0 + 4);
    s16x8 a;
    #pragma unroll
    for (int j = 0; j < 4; j++){ a[j] = (short)f2bf(x0[j]); a[4 + j] = (short)f2bf(x1[j]); }
    *(s16x8*)(xb + row * 768 + k0) = a;
    #pragma unroll
    for (int nf = 0; nf < 7; nf++){
      s16x8 b = *(const s16x8*)(tokensb + (nf * 16 + l15) * 768 + k0);
      acc[nf] = __builtin_amdgcn_mfma_f32_16x16x32_bf16(a, b, acc[nf], 0, 0, 0);
    }
  }

  const float sc = 0.03608439182435161f; // 768^-0.5
  #pragma unroll
  for (int r = 0; r < 4; r++){
    float mx = -1e30f;
    #pragma unroll
    for (int nf = 0; nf < 7; nf++){
      int col = nf * 16 + l15;
      float v = acc[nf][r] * sc;
      if (col < 100 && v > mx) mx = v;
    }
    mx = fmaxf(mx, __shfl_xor(mx, 1));
    mx = fmaxf(mx, __shfl_xor(mx, 2));
    mx = fmaxf(mx, __shfl_xor(mx, 4));
    mx = fmaxf(mx, __shfl_xor(mx, 8));
    float p[7], sm = 0.f;
    #pragma unroll
    for (int nf = 0; nf < 7; nf++){
      int col = nf * 16 + l15;
      float v = (col < 100) ? __expf(acc[nf][r] * sc - mx) : 0.f;
      p[nf] = v; sm += v;
    }
    sm += __shfl_xor(sm, 1);
    sm += __shfl_xor(sm, 2);
    sm += __shfl_xor(sm, 4);
    sm += __shfl_xor(sm, 8);
    float inv = 1.f / sm;
    long prow = wrowg + lhi * 4 + r;
    #pragma unroll
    for (int nf = 0; nf < 7; nf++)
      Pbuf[prow * 128 + nf * 16 + l15] = f2bf(p[nf] * inv);
    Pbuf[prow * 128 + 112 + l15] = 0;
  }
}

// ---------------- big GEMM: out = feats + scale*([xb|P] @ WB^T + bf), 2-phase dbuf ----------------
__global__ __launch_bounds__(256) void k_gemm(const unsigned short* __restrict__ xb,
    const unsigned short* __restrict__ Pbuf, const unsigned short* __restrict__ WB,
    const float* __restrict__ bfv, const float* __restrict__ scalep,
    float* __restrict__ outf){
  __shared__ __align__(16) unsigned short As[2][128 * 64];
  __shared__ __align__(16) unsigned short Bs[2][128 * 64];
  int bid = blockIdx.x;                 // 1536 = 8 XCD * 192
  int sid = (bid & 7) * 192 + (bid >> 3);
  int mt = sid / 6, nt = sid - mt * 6;
  long brow = (long)mt * 128;
  int bcol = nt * 128;
  int tid = threadIdx.x, w = tid >> 6, l = tid & 63;
  int l15 = l & 15, lhi = l >> 4;
  int srow = l >> 3, scol = (l & 7) * 8;
  int wrow = (w >> 1) * 64, wcol = (w & 1) * 64;

  f32x4 acc[4][4];
  #pragma unroll
  for (int m = 0; m < 4; m++)
    #pragma unroll
    for (int n = 0; n < 4; n++) acc[m][n] = (f32x4)0.0f;

  #define STAGE(BUF, T) { \
    _Pragma("unroll") \
    for (int i = 0; i < 4; i++){ \
      int c = i * 4 + w; \
      int rr = c * 8 + srow; \
      const unsigned short* ga = ((T) < 12) \
        ? xb   + (brow + rr) * 768 + (T) * 64 + scol \
        : Pbuf + (brow + rr) * 128 + ((T) - 12) * 64 + scol; \
      GLDS16(ga, As[BUF] + c * 512); \
      const unsigned short* gb = WB + (long)(bcol + rr) * 896 + (T) * 64 + scol; \
      GLDS16(gb, Bs[BUF] + c * 512); \
    } }

  STAGE(0, 0);
  for (int t = 0; t < 14; t++){
    int cur = t & 1;
    __syncthreads();                      // drains vmcnt -> buf[cur] ready; protects buf[cur^1]
    if (t + 1 < 14) STAGE(cur ^ 1, t + 1);
    #pragma unroll
    for (int kk = 0; kk < 2; kk++){
      s16x8 a[4], b[4];
      #pragma unroll
      for (int m = 0; m < 4; m++)
        a[m] = *(const s16x8*)(As[cur] + (wrow + m * 16 + l15) * 64 + kk * 32 + lhi * 8);
      #pragma unroll
      for (int n = 0; n < 4; n++)
        b[n] = *(const s16x8*)(Bs[cur] + (wcol + n * 16 + l15) * 64 + kk * 32 + lhi * 8);
      #pragma unroll
      for (int m = 0; m < 4; m++)
        #pragma unroll
        for (int n = 0; n < 4; n++)
          acc[m][n] = __builtin_amdgcn_mfma_f32_16x16x32_bf16(a[m], b[n], acc[m][n], 0, 0, 0);
    }
  }
  #undef STAGE

  float scale = *scalep;
  #pragma unroll
  for (int m = 0; m < 4; m++){
    #pragma unroll
    for (int n = 0; n < 4; n++){
      int gcol = bcol + wcol + n * 16 + l15;
      float bias = bfv[gcol];
      #pragma unroll
      for (int r = 0; r < 4; r++){
        long grow = brow + wrow + m * 16 + lhi * 4 + r;
        float feat = bf2f(xb[grow * 768 + gcol]);
        outf[grow * 768 + gcol] = feat + scale * (acc[m][n][r] + bias);
      }
    }
  }
}

extern "C" void kernel_launch(void* const* d_in, const int* in_sizes, int n_in,
                              void* d_out, int out_size, void* d_ws, size_t ws_size,
                              hipStream_t stream) {
  const float* x   = (const float*)d_in[0];
  const float* Wd  = (const float*)d_in[1];
  const float* bd  = (const float*)d_in[2];
  const float* Wu  = (const float*)d_in[3];
  const float* bu  = (const float*)d_in[4];
  const float* Wt  = (const float*)d_in[5];
  const float* bt  = (const float*)d_in[6];
  const float* Wf  = (const float*)d_in[7];
  const float* bfv = (const float*)d_in[8];
  const float* Ap  = (const float*)d_in[9];
  const float* Bp  = (const float*)d_in[10];
  const float* scalep = (const float*)d_in[11];
  const int* layerp   = (const int*)d_in[12];
  float* out = (float*)d_out;

  char* ws = (char*)d_ws;
  unsigned short* xb      = (unsigned short*)(ws);              // 50,331,648
  unsigned short* Pbuf    = (unsigned short*)(ws + 50331648);   //  8,388,608
  unsigned short* WB      = (unsigned short*)(ws + 58720256);   //  1,376,256 (768 x 896)
  unsigned short* Wtb     = (unsigned short*)(ws + 60096512);   //  1,179,648 (768 x 768)
  unsigned short* tokensb = (unsigned short*)(ws + 61276160);   //    172,032 (112 x 768)
  unsigned short* t2fb    = (unsigned short*)(ws + 61448192);   //    172,032 (112 x 768)
  unsigned short* Ab      = (unsigned short*)(ws + 61620224);   //     57,344 (112 x 256)
  unsigned short* Blb     = (unsigned short*)(ws + 61677568);   //    131,072 (256 x 256)
  unsigned short* Wdb     = (unsigned short*)(ws + 61808640);   //     49,152 ( 96 x 256)
  unsigned short* Wub     = (unsigned short*)(ws + 61857792);   //    147,456 (768 x  96)
  unsigned short* hb      = (unsigned short*)(ws + 62005248);   //     49,152 (256 x  96)
  unsigned short* Bfmt    = (unsigned short*)(ws + 62054400);   //    393,216 (768 x 256, Bf transposed)

  const float* xf = x + 32 * 768;   // feats (skip cls rows)
  float* outf = out + 32 * 768;

  // cls passthrough
  hipMemcpyAsync(d_out, d_in[0], 32 * 768 * sizeof(float), hipMemcpyDeviceToDevice, stream);

  k_prep<<<dim3(2688, 6), 256, 0, stream>>>(Wd, Wu, Wt, Wf, Ap, Bp, layerp,
                                            Wdb, Wub, Wtb, WB, Ab, Blb);
  // h = gelu(Bl @ Wd^T + bd)            (256 x 96, K=256)
  k_mm<0><<<dim3(16, 6),  64, 0, stream>>>(Blb, 256, Wdb, 256, 256, bd, hb, 96);
  // Bf^T = (h @ Wu^T + bu)^T            (768 x 256 store, K=96)
  k_mm<1><<<dim3(16, 48), 64, 0, stream>>>(hb, 96, Wub, 96, 96, bu, Bfmt, 256);
  // tokens = A @ Bf                     (112 x 768, K=256)
  k_mm<2><<<dim3(7, 48),  64, 0, stream>>>(Ab, 256, Bfmt, 256, 256, nullptr, tokensb, 768);
  // t2f = tokens @ Wt^T + bt            (112 x 768, K=768)
  k_mm<2><<<dim3(7, 48),  64, 0, stream>>>(tokensb, 768, Wtb, 768, 768, bt, t2fb, 768);
  // G' = t2f @ Wf^T  -> WB[:, 768:880]  (transposed store, K=768)
  k_mm<3><<<dim3(7, 48),  64, 0, stream>>>(t2fb, 768, WB, 896, 768, nullptr, WB, 0);

  k_attn<<<512, 256, 0, stream>>>(xf, tokensb, xb, Pbuf);
  k_gemm<<<1536, 256, 0, stream>>>(xb, Pbuf, WB, bfv, scalep, outf);
}

// Round 3
// 174.230 us; speedup vs baseline: 1.6894x; 1.1517x over previous
//
#include <hip/hip_runtime.h>
#include <hip/hip_bf16.h>
#include <cmath>

using f32x4 = __attribute__((ext_vector_type(4))) float;
using s16x8 = __attribute__((ext_vector_type(8))) short;

__device__ __forceinline__ float bf2f(unsigned short u){
  union { unsigned int i; float f; } v; v.i = ((unsigned int)u) << 16; return v.f;
}
__device__ __forceinline__ unsigned short f2bf(float f){
  union { float f; unsigned int i; } v; v.f = f;
  return (unsigned short)((v.i + 0x7FFFu + ((v.i >> 16) & 1u)) >> 16);
}

#define GLDS16(g, l) __builtin_amdgcn_global_load_lds( \
    (const __attribute__((address_space(1))) unsigned int*)(g), \
    (__attribute__((address_space(3))) unsigned int*)(l), 16, 0, 0)

// ---------------- prep: convert all small operands to bf16 ----------------
__global__ void k_prep(const float* __restrict__ Wd, const float* __restrict__ Wu,
                       const float* __restrict__ Wt, const float* __restrict__ Wf,
                       const float* __restrict__ Ap, const float* __restrict__ Bp,
                       const int* __restrict__ layerp,
                       unsigned short* __restrict__ Wdb, unsigned short* __restrict__ Wub,
                       unsigned short* __restrict__ Wtb, unsigned short* __restrict__ WB,
                       unsigned short* __restrict__ Ab, unsigned short* __restrict__ Blb){
  int idx = blockIdx.x * 256 + threadIdx.x;
  switch (blockIdx.y){
    case 0: if (idx < 24576)  Wdb[idx] = f2bf(Wd[idx]); break;
    case 1: if (idx < 73728)  Wub[idx] = f2bf(Wu[idx]); break;
    case 2: if (idx < 589824) Wtb[idx] = f2bf(Wt[idx]); break;
    case 3: if (idx < 688128){
      int n = idx / 896, c = idx - n * 896;
      WB[idx] = (c < 768) ? f2bf(Wf[n * 768 + c]) : (unsigned short)0;
    } break;
    case 4: if (idx < 28672){
      int r = idx >> 8;
      Ab[idx] = (r < 100) ? f2bf(Ap[idx]) : (unsigned short)0;
    } break;
    case 5: if (idx < 65536) Blb[idx] = f2bf(Bp[(long)(*layerp) * 65536 + idx]); break;
  }
}

// ---------------- generic 1-wave MFMA mini-GEMM: out = epi(A @ B^T + bias) ----------------
template<int EPI>
__global__ __launch_bounds__(64) void k_mm(const unsigned short* __restrict__ A, int lda,
    const unsigned short* __restrict__ B, int ldb, int K,
    const float* __restrict__ bias, unsigned short* __restrict__ out, int ldo){
  int l = threadIdx.x, l15 = l & 15, lhi = l >> 4;
  int m0 = blockIdx.x * 16, n0 = blockIdx.y * 16;
  f32x4 acc = (f32x4)0.0f;
  #pragma unroll 4
  for (int k0 = 0; k0 < K; k0 += 32){
    s16x8 a = *(const s16x8*)(A + (long)(m0 + l15) * lda + k0 + lhi * 8);
    s16x8 b = *(const s16x8*)(B + (long)(n0 + l15) * ldb + k0 + lhi * 8);
    acc = __builtin_amdgcn_mfma_f32_16x16x32_bf16(a, b, acc, 0, 0, 0);
  }
  int col = n0 + l15;
  float bv = bias ? bias[col] : 0.0f;
  #pragma unroll
  for (int r = 0; r < 4; r++){
    int row = m0 + lhi * 4 + r;
    float v = acc[r] + bv;
    if (EPI == 0){
      v = 0.5f * v * (1.0f + erff(v * 0.70710678118654752f));
      out[(long)row * ldo + col] = f2bf(v);
    } else if (EPI == 1){
      out[(long)col * ldo + row] = f2bf(v);
    } else if (EPI == 2){
      out[(long)row * ldo + col] = f2bf(v);
    } else {
      out[(long)col * 896 + 768 + row] = (row < 100) ? f2bf(v) : (unsigned short)0;
    }
  }
}

// ---------------- fused cvt + logits + softmax: reads f32 feats, writes xb + Pbuf ----------------
__global__ __launch_bounds__(256) void k_attn(const float* __restrict__ xf,
    const unsigned short* __restrict__ tokensb, unsigned short* __restrict__ xb,
    unsigned short* __restrict__ Pbuf){
  int tid = threadIdx.x;
  int w = tid >> 6, l = tid & 63;
  int l15 = l & 15, lhi = l >> 4;
  long wrowg = (long)blockIdx.x * 64 + w * 16;   // wave covers 16 rows

  f32x4 acc[7];
  #pragma unroll
  for (int nf = 0; nf < 7; nf++) acc[nf] = (f32x4)0.0f;

  long row = wrowg + l15;
  for (int t = 0; t < 24; t++){
    int k0 = t * 32 + lhi * 8;
    f32x4 x0 = *(const f32x4*)(xf + row * 768 + k0);
    f32x4 x1 = *(const f32x4*)(xf + row * 768 + k0 + 4);
    s16x8 a;
    #pragma unroll
    for (int j = 0; j < 4; j++){ a[j] = (short)f2bf(x0[j]); a[4 + j] = (short)f2bf(x1[j]); }
    *(s16x8*)(xb + row * 768 + k0) = a;
    #pragma unroll
    for (int nf = 0; nf < 7; nf++){
      s16x8 b = *(const s16x8*)(tokensb + (nf * 16 + l15) * 768 + k0);
      acc[nf] = __builtin_amdgcn_mfma_f32_16x16x32_bf16(a, b, acc[nf], 0, 0, 0);
    }
  }

  const float sc = 0.03608439182435161f; // 768^-0.5
  #pragma unroll
  for (int r = 0; r < 4; r++){
    float mx = -1e30f;
    #pragma unroll
    for (int nf = 0; nf < 7; nf++){
      int col = nf * 16 + l15;
      float v = acc[nf][r] * sc;
      if (col < 100 && v > mx) mx = v;
    }
    mx = fmaxf(mx, __shfl_xor(mx, 1));
    mx = fmaxf(mx, __shfl_xor(mx, 2));
    mx = fmaxf(mx, __shfl_xor(mx, 4));
    mx = fmaxf(mx, __shfl_xor(mx, 8));
    float p[7], sm = 0.f;
    #pragma unroll
    for (int nf = 0; nf < 7; nf++){
      int col = nf * 16 + l15;
      float v = (col < 100) ? __expf(acc[nf][r] * sc - mx) : 0.f;
      p[nf] = v; sm += v;
    }
    sm += __shfl_xor(sm, 1);
    sm += __shfl_xor(sm, 2);
    sm += __shfl_xor(sm, 4);
    sm += __shfl_xor(sm, 8);
    float inv = 1.f / sm;
    long prow = wrowg + lhi * 4 + r;
    #pragma unroll
    for (int nf = 0; nf < 7; nf++)
      Pbuf[prow * 128 + nf * 16 + l15] = f2bf(p[nf] * inv);
    Pbuf[prow * 128 + 112 + l15] = 0;
  }
}

// ---------------- big GEMM: out = feats + scale*([xb|P] @ WB^T + bf) ----------------
// BM=256 BN=128 BK=64, 8 waves (4Mx2N), tribuf LDS, counted vmcnt, T2 swizzle, T5 setprio.
__global__ __launch_bounds__(512, 2) void k_gemm(const unsigned short* __restrict__ xb,
    const unsigned short* __restrict__ Pbuf, const unsigned short* __restrict__ WB,
    const float* __restrict__ bfv, const float* __restrict__ scalep,
    float* __restrict__ outf){
  extern __shared__ __align__(16) unsigned short lds[];   // 3 * (256*64 + 128*64) ushorts
  int bid = blockIdx.x;                 // 768 = 8 XCD * 96
  int sid = (bid & 7) * 96 + (bid >> 3);
  int mt = sid / 6, nt = sid - mt * 6;
  long brow = (long)mt * 256;
  int bcol = nt * 128;
  int tid = threadIdx.x, w = tid >> 6, l = tid & 63;
  int l15 = l & 15, lhi = l >> 4;
  int wr = w >> 1, wc = w & 1;          // wave tile: rows wr*64.., cols wc*64..
  int lrow = l >> 3;                    // 0..7 (row within 8-row staging stripe)
  int lsw  = ((l & 7) ^ lrow) * 8;      // pre-swizzled source col (ushorts): T2 both-sides rule

  f32x4 acc[4][4];
  #pragma unroll
  for (int m = 0; m < 4; m++)
    #pragma unroll
    for (int n = 0; n < 4; n++) acc[m][n] = (f32x4)0.0f;

  // STAGE: 4 A-issues (256x64) + 2 B-issues (128x64); linear LDS dest, swizzled source.
  #define STAGE(BUF, T) { \
    int koff = (T) * 64; \
    _Pragma("unroll") \
    for (int i = 0; i < 4; i++){ \
      int r = (w * 4 + i) * 8 + lrow; \
      const unsigned short* ga = ((T) < 12) \
        ? xb   + (brow + r) * 768 + koff + lsw \
        : Pbuf + (brow + r) * 128 + ((T) - 12) * 64 + lsw; \
      GLDS16(ga, lds + (BUF) * 24576 + (w * 4 + i) * 512); \
    } \
    _Pragma("unroll") \
    for (int i = 0; i < 2; i++){ \
      int r = (w * 2 + i) * 8 + lrow; \
      const unsigned short* gb = WB + (long)(bcol + r) * 896 + koff + lsw; \
      GLDS16(gb, lds + (BUF) * 24576 + 16384 + (w * 2 + i) * 512); \
    } }

  STAGE(0, 0);
  STAGE(1, 1);
  for (int t = 0; t < 14; t++){
    if (t < 13) asm volatile("s_waitcnt vmcnt(6)" ::: "memory");
    else        asm volatile("s_waitcnt vmcnt(0)" ::: "memory");
    __builtin_amdgcn_s_barrier();
    if (t < 12){
      int nb = t + 2 - ((t + 2) >= 3 ? 3 : 0); nb -= (nb >= 3 ? 3 : 0); // (t+2)%3 cheap
      STAGE(nb, t + 2);
    }
    const unsigned short* Ab = lds + (t % 3) * 24576;
    const unsigned short* Bb = Ab + 16384;
    __builtin_amdgcn_s_setprio(1);
    #pragma unroll
    for (int kk = 0; kk < 2; kk++){
      s16x8 a[4], b[4];
      #pragma unroll
      for (int m = 0; m < 4; m++){
        int ar = wr * 64 + m * 16 + l15;
        int xoff = (kk * 64 + lhi * 16) ^ ((ar & 7) << 4);   // swizzled byte col
        a[m] = *(const s16x8*)(Ab + ar * 64 + (xoff >> 1));
      }
      #pragma unroll
      for (int n = 0; n < 4; n++){
        int br = wc * 64 + n * 16 + l15;
        int xoff = (kk * 64 + lhi * 16) ^ ((br & 7) << 4);
        b[n] = *(const s16x8*)(Bb + br * 64 + (xoff >> 1));
      }
      #pragma unroll
      for (int m = 0; m < 4; m++)
        #pragma unroll
        for (int n = 0; n < 4; n++)
          acc[m][n] = __builtin_amdgcn_mfma_f32_16x16x32_bf16(a[m], b[n], acc[m][n], 0, 0, 0);
    }
    __builtin_amdgcn_s_setprio(0);
  }
  #undef STAGE

  float scale = *scalep;
  #pragma unroll
  for (int m = 0; m < 4; m++){
    #pragma unroll
    for (int n = 0; n < 4; n++){
      int gcol = bcol + wc * 64 + n * 16 + l15;
      float bias = bfv[gcol];
      #pragma unroll
      for (int r = 0; r < 4; r++){
        long grow = brow + wr * 64 + m * 16 + lhi * 4 + r;
        float feat = bf2f(xb[grow * 768 + gcol]);
        outf[grow * 768 + gcol] = feat + scale * (acc[m][n][r] + bias);
      }
    }
  }
}

extern "C" void kernel_launch(void* const* d_in, const int* in_sizes, int n_in,
                              void* d_out, int out_size, void* d_ws, size_t ws_size,
                              hipStream_t stream) {
  const float* x   = (const float*)d_in[0];
  const float* Wd  = (const float*)d_in[1];
  const float* bd  = (const float*)d_in[2];
  const float* Wu  = (const float*)d_in[3];
  const float* bu  = (const float*)d_in[4];
  const float* Wt  = (const float*)d_in[5];
  const float* bt  = (const float*)d_in[6];
  const float* Wf  = (const float*)d_in[7];
  const float* bfv = (const float*)d_in[8];
  const float* Ap  = (const float*)d_in[9];
  const float* Bp  = (const float*)d_in[10];
  const float* scalep = (const float*)d_in[11];
  const int* layerp   = (const int*)d_in[12];
  float* out = (float*)d_out;

  char* ws = (char*)d_ws;
  unsigned short* xb      = (unsigned short*)(ws);              // 50,331,648
  unsigned short* Pbuf    = (unsigned short*)(ws + 50331648);   //  8,388,608
  unsigned short* WB      = (unsigned short*)(ws + 58720256);   //  1,376,256 (768 x 896)
  unsigned short* Wtb     = (unsigned short*)(ws + 60096512);   //  1,179,648 (768 x 768)
  unsigned short* tokensb = (unsigned short*)(ws + 61276160);   //    172,032 (112 x 768)
  unsigned short* t2fb    = (unsigned short*)(ws + 61448192);   //    172,032 (112 x 768)
  unsigned short* Ab      = (unsigned short*)(ws + 61620224);   //     57,344 (112 x 256)
  unsigned short* Blb     = (unsigned short*)(ws + 61677568);   //    131,072 (256 x 256)
  unsigned short* Wdb     = (unsigned short*)(ws + 61808640);   //     49,152 ( 96 x 256)
  unsigned short* Wub     = (unsigned short*)(ws + 61857792);   //    147,456 (768 x  96)
  unsigned short* hb      = (unsigned short*)(ws + 62005248);   //     49,152 (256 x  96)
  unsigned short* Bfmt    = (unsigned short*)(ws + 62054400);   //    393,216 (768 x 256, Bf^T)

  const float* xf = x + 32 * 768;   // feats (skip cls rows)
  float* outf = out + 32 * 768;

  static int lds_attr_set = 0;
  if (!lds_attr_set){   // host-side attribute, not a stream op; idempotent & deterministic
    hipFuncSetAttribute((const void*)k_gemm, hipFuncAttributeMaxDynamicSharedMemorySize, 147456);
    lds_attr_set = 1;
  }

  // cls passthrough
  hipMemcpyAsync(d_out, d_in[0], 32 * 768 * sizeof(float), hipMemcpyDeviceToDevice, stream);

  k_prep<<<dim3(2688, 6), 256, 0, stream>>>(Wd, Wu, Wt, Wf, Ap, Bp, layerp,
                                            Wdb, Wub, Wtb, WB, Ab, Blb);
  // h = gelu(Bl @ Wd^T + bd)            (256 x 96, K=256)
  k_mm<0><<<dim3(16, 6),  64, 0, stream>>>(Blb, 256, Wdb, 256, 256, bd, hb, 96);
  // Bf^T = (h @ Wu^T + bu)^T            (768 x 256 store, K=96)
  k_mm<1><<<dim3(16, 48), 64, 0, stream>>>(hb, 96, Wub, 96, 96, bu, Bfmt, 256);
  // tokens = A @ Bf                     (112 x 768, K=256)
  k_mm<2><<<dim3(7, 48),  64, 0, stream>>>(Ab, 256, Bfmt, 256, 256, nullptr, tokensb, 768);
  // t2f = tokens @ Wt^T + bt            (112 x 768, K=768)
  k_mm<2><<<dim3(7, 48),  64, 0, stream>>>(tokensb, 768, Wtb, 768, 768, bt, t2fb, 768);
  // G' = t2f @ Wf^T  -> WB[:, 768:880]  (transposed store, K=768)
  k_mm<3><<<dim3(7, 48),  64, 0, stream>>>(t2fb, 768, WB, 896, 768, nullptr, WB, 0);

  k_attn<<<512, 256, 0, stream>>>(xf, tokensb, xb, Pbuf);
  k_gemm<<<768, 512, 147456, stream>>>(xb, Pbuf, WB, bfv, scalep, outf);
}